// Round 1
// baseline (314.865 us; speedup 1.0000x reference)
//
#include <hip/hip_runtime.h>

// Problem constants (match reference)
#define D       32
#define B       2048
#define M       65536
#define MTILES  128
#define MTILE   (M / MTILES)   // 512
#define BTILE   256

// ws layout (floats):
//   [0, M)                      : wnorm_half[m] = 0.5*||w_m||^2
//   [M, M + B*MTILES)           : partial best score  [b][mt]
//   [M + B*MTILES, + B*MTILES)  : partial best index  [b][mt] (as int)

// ---------------------------------------------------------------------------
// Kernel 0: half squared norms of codebook rows. 4 threads per row, coalesced
// float4 loads (4 lanes cover one contiguous 128B row), shuffle-reduce.
// Also warms L2/L3 with w for the main pass.
// ---------------------------------------------------------------------------
__global__ void som_wnorm_kernel(const float* __restrict__ w,
                                 float* __restrict__ wnorm) {
    int t   = blockIdx.x * blockDim.x + threadIdx.x;  // M*4 threads total
    int row = t >> 2;
    int j   = t & 3;
    const float4* p = (const float4*)(w + (size_t)row * D) + j * 2;
    float4 a = p[0];
    float4 b4 = p[1];
    float s = a.x * a.x + a.y * a.y + a.z * a.z + a.w * a.w
            + b4.x * b4.x + b4.y * b4.y + b4.z * b4.z + b4.w * b4.w;
    s += __shfl_xor(s, 1);
    s += __shfl_xor(s, 2);
    if (j == 0) wnorm[row] = 0.5f * s;
}

// ---------------------------------------------------------------------------
// Kernel 1: per-(b, mtile) partial argmax of score = x.w - 0.5||w||^2.
// Thread owns one batch row (x in 32 VGPRs). m is wave-uniform -> w row loads
// should compile to scalar s_load feeding v_fmac with SGPR operand.
// Strict '>' update + ascending m gives lowest-index tie-break within a tile.
// ---------------------------------------------------------------------------
__global__ __launch_bounds__(BTILE, 8)
void som_score_kernel(const float* __restrict__ x,
                      const float* __restrict__ w,
                      const float* __restrict__ wnorm,
                      float* __restrict__ pscore,
                      int*   __restrict__ pidx) {
    const int bt = blockIdx.x;          // 0..7   batch tile
    const int mt = blockIdx.y;          // 0..127 m tile
    const int b  = bt * BTILE + threadIdx.x;

    // x row -> registers
    float xr[D];
    const float4* xp = (const float4*)(x + (size_t)b * D);
#pragma unroll
    for (int i = 0; i < D / 4; i++) {
        float4 v = xp[i];
        xr[4 * i + 0] = v.x; xr[4 * i + 1] = v.y;
        xr[4 * i + 2] = v.z; xr[4 * i + 3] = v.w;
    }

    const int m0 = mt * MTILE;
    float best = -3.0e38f;
    int   bidx = m0;

#pragma unroll 2
    for (int mm = 0; mm < MTILE; mm++) {
        const int m = m0 + mm;                      // wave-uniform
        const float* __restrict__ wr = w + (size_t)m * D;
        float acc = 0.0f;
#pragma unroll
        for (int i = 0; i < D; i++) acc = fmaf(xr[i], wr[i], acc);
        const float score = acc - wnorm[m];
        if (score > best) { best = score; bidx = m; }
    }

    pscore[(size_t)b * MTILES + mt] = best;
    pidx  [(size_t)b * MTILES + mt] = bidx;
}

// ---------------------------------------------------------------------------
// Kernel 2: reduce partials per batch row, tie-break to lowest index, gather
// grid coords. 2048 threads.
// ---------------------------------------------------------------------------
__global__ void som_reduce_kernel(const float* __restrict__ pscore,
                                  const int*   __restrict__ pidx,
                                  const float* __restrict__ grid_flat,
                                  float* __restrict__ out) {
    const int b = blockIdx.x * blockDim.x + threadIdx.x;
    const float* ps = pscore + (size_t)b * MTILES;
    const int*   pi = pidx   + (size_t)b * MTILES;

    float best = -3.0e38f;
    int   bidx = 0x7fffffff;
#pragma unroll 4
    for (int t = 0; t < MTILES; t++) {
        const float s  = ps[t];
        const int   id = pi[t];
        if (s > best || (s == best && id < bidx)) { best = s; bidx = id; }
    }
    const float2 g = ((const float2*)grid_flat)[bidx];
    ((float2*)out)[b] = g;
}

// ---------------------------------------------------------------------------
extern "C" void kernel_launch(void* const* d_in, const int* in_sizes, int n_in,
                              void* d_out, int out_size, void* d_ws, size_t ws_size,
                              hipStream_t stream) {
    const float* x         = (const float*)d_in[0];   // [B, D]
    const float* grid_flat = (const float*)d_in[1];   // [1, M, 2]
    const float* w         = (const float*)d_in[2];   // [1, M, D]
    float* out = (float*)d_out;                       // [B, 2]

    float* wnorm  = (float*)d_ws;                     // M floats
    float* pscore = wnorm + M;                        // B*MTILES floats
    int*   pidx   = (int*)(pscore + (size_t)B * MTILES);

    // Kernel 0: 0.5*||w||^2  (M rows, 4 threads/row)
    som_wnorm_kernel<<<(M * 4) / 256, 256, 0, stream>>>(w, wnorm);

    // Kernel 1: partial argmax per (b, mtile)
    dim3 grid1(B / BTILE, MTILES);
    som_score_kernel<<<grid1, BTILE, 0, stream>>>(x, w, wnorm, pscore, pidx);

    // Kernel 2: final reduce + gather
    som_reduce_kernel<<<B / 256, 256, 0, stream>>>(pscore, pidx, grid_flat, out);
}

// Round 2
// 111.459 us; speedup vs baseline: 2.8250x; 2.8250x over previous
//
#include <hip/hip_runtime.h>
#include <stdint.h>

// Problem constants
#define D       32
#define B       2048
#define M       65536
#define STRIPS  1024          // M / 64 rows per strip
#define CHUNKS  4             // batch chunks per strip (one per wave in block)
#define CHCOLS  (B / CHUNKS)  // 512 cols per chunk
#define NTILES  (CHCOLS / 16) // 32 16-col tiles per wave-job
#define SGROUPS 32            // strip groups in reduce1
#define SPERG   (STRIPS / SGROUPS)  // 32 strips per group

typedef _Float16 half8 __attribute__((ext_vector_type(8)));
typedef float    floatx4 __attribute__((ext_vector_type(4)));

// ---------------------------------------------------------------------------
// fast-path ws layout (16B aligned):
//   [0,       128K)   x_hi  _Float16[B*D]
//   [128K,    256K)   x_lo  _Float16[B*D]
//   [256K,    512K)   wnorm float[M]     (0.5*||w||^2)
//   [512K,    512K+16M)  pkeys uint64[STRIPS * B]
//   [+16M,    +512K)  s2    uint64[SGROUPS * B]
// ---------------------------------------------------------------------------

// ============ shared prep: 0.5*||w||^2 (also used by fallback) =============
__global__ void som_wnorm_kernel(const float* __restrict__ w,
                                 float* __restrict__ wnorm) {
    int t   = blockIdx.x * blockDim.x + threadIdx.x;  // M*4 threads
    int row = t >> 2;
    int j   = t & 3;
    const float4* p = (const float4*)(w + (size_t)row * D) + j * 2;
    float4 a = p[0];
    float4 b4 = p[1];
    float s = a.x * a.x + a.y * a.y + a.z * a.z + a.w * a.w
            + b4.x * b4.x + b4.y * b4.y + b4.z * b4.z + b4.w * b4.w;
    s += __shfl_xor(s, 1);
    s += __shfl_xor(s, 2);
    if (j == 0) wnorm[row] = 0.5f * s;
}

// ============ prep: split x into fp16 hi/lo ================================
__global__ void split_x_kernel(const float* __restrict__ x,
                               _Float16* __restrict__ xh,
                               _Float16* __restrict__ xl) {
    int i = blockIdx.x * blockDim.x + threadIdx.x;   // B*D threads
    float v = x[i];
    _Float16 h = (_Float16)v;
    xh[i] = h;
    xl[i] = (_Float16)(v - (float)h);
}

// ============ main: MFMA scores + per-strip argmax partials ================
// Wave owns a 64-row w strip (A, converted to f16 hi/lo in-register), loops
// over a 512-col batch chunk (B-frags from x_hi/x_lo). score = x.w - wnorm.
// Per 16-col tile: 12 MFMAs, per-lane argmax over 16 C regs, u64-key
// butterfly across quads, one 8B partial store per lane<16.
__global__ __launch_bounds__(256, 4)
void som_mfma_kernel(const float* __restrict__ w,
                     const float* __restrict__ wnorm,
                     const _Float16* __restrict__ x_hi,
                     const _Float16* __restrict__ x_lo,
                     uint64_t* __restrict__ pkeys) {
    const int s    = blockIdx.x;            // strip 0..1023
    const int wv   = threadIdx.x >> 6;      // chunk 0..3
    const int lane = threadIdx.x & 63;
    const int q    = lane >> 4;             // quad 0..3
    const int j    = lane & 15;

    // A-frags: w strip rows, fp32 -> f16 hi/lo split in registers.
    // A[m=lane&15][k=q*8+kk] per 16x16x32 layout; 4 row-tiles cover 64 rows.
    half8 a_hi[4], a_lo[4];
#pragma unroll
    for (int t = 0; t < 4; t++) {
        const float* wp = w + (size_t)(s * 64 + t * 16 + j) * D + q * 8;
        float4 f0 = ((const float4*)wp)[0];
        float4 f1 = ((const float4*)wp)[1];
        float f[8] = {f0.x, f0.y, f0.z, f0.w, f1.x, f1.y, f1.z, f1.w};
#pragma unroll
        for (int k = 0; k < 8; k++) {
            _Float16 h = (_Float16)f[k];
            a_hi[t][k] = h;
            a_lo[t][k] = (_Float16)(f[k] - (float)h);
        }
    }

    // wnorm for this lane's C rows: row = t*16 + q*4 + r
    float wn[4][4];
#pragma unroll
    for (int t = 0; t < 4; t++)
#pragma unroll
        for (int r = 0; r < 4; r++)
            wn[t][r] = wnorm[s * 64 + t * 16 + q * 4 + r];

    uint64_t* pk = pkeys + (size_t)s * B;

    for (int it = 0; it < NTILES; it++) {
        const int nb  = wv * CHCOLS + it * 16;
        const int col = nb + j;
        const half8 bh = *(const half8*)(x_hi + (size_t)col * D + q * 8);
        const half8 bl = *(const half8*)(x_lo + (size_t)col * D + q * 8);

        floatx4 acc[4];
#pragma unroll
        for (int t = 0; t < 4; t++)
            acc[t] = __builtin_amdgcn_mfma_f32_16x16x32_f16(
                a_lo[t], bh, (floatx4){0.f, 0.f, 0.f, 0.f}, 0, 0, 0);
#pragma unroll
        for (int t = 0; t < 4; t++)
            acc[t] = __builtin_amdgcn_mfma_f32_16x16x32_f16(a_hi[t], bl, acc[t], 0, 0, 0);
#pragma unroll
        for (int t = 0; t < 4; t++)
            acc[t] = __builtin_amdgcn_mfma_f32_16x16x32_f16(a_hi[t], bh, acc[t], 0, 0, 0);

        // per-lane argmax over 16 C regs (rows ascending in (t,r) for fixed q
        // => strict '>' keeps lowest index on ties)
        float best = -3.4e38f;
        int   brow = 0;
#pragma unroll
        for (int t = 0; t < 4; t++)
#pragma unroll
            for (int r = 0; r < 4; r++) {
                float sc  = acc[t][r] - wn[t][r];
                int   row = s * 64 + t * 16 + q * 4 + r;
                if (sc > best) { best = sc; brow = row; }
            }

        // sortable key: monotone float bits <<32 | ~row (max => high score,
        // then lowest row). Associative max => deterministic.
        uint32_t u = __float_as_uint(best);
        u ^= (uint32_t)((int32_t)u >> 31) | 0x80000000u;
        uint64_t key = ((uint64_t)u << 32) | (uint64_t)(~(uint32_t)brow);

        // butterfly max across the 4 quads (same col j)
        uint64_t o;
        o = (uint64_t)__shfl_xor((long long)key, 16); if (o > key) key = o;
        o = (uint64_t)__shfl_xor((long long)key, 32); if (o > key) key = o;

        if (lane < 16) pk[col] = key;
    }
}

// ============ reduce1: max over strips within group =======================
__global__ void som_reduce1_kernel(const uint64_t* __restrict__ pkeys,
                                   uint64_t* __restrict__ s2) {
    const int col = blockIdx.x * 256 + threadIdx.x;  // gridDim.x = 8
    const int sg  = blockIdx.y;                      // 0..SGROUPS-1
    uint64_t best = 0;
#pragma unroll 8
    for (int t = 0; t < SPERG; t++) {
        uint64_t k = pkeys[(size_t)(sg * SPERG + t) * B + col];
        if (k > best) best = k;
    }
    s2[(size_t)sg * B + col] = best;
}

// ============ reduce2: final max + grid gather ============================
__global__ void som_reduce2_kernel(const uint64_t* __restrict__ s2,
                                   const float* __restrict__ grid_flat,
                                   float* __restrict__ out) {
    const int b = blockIdx.x * 256 + threadIdx.x;    // B threads
    uint64_t best = 0;
#pragma unroll
    for (int sg = 0; sg < SGROUPS; sg++) {
        uint64_t k = s2[(size_t)sg * B + b];
        if (k > best) best = k;
    }
    uint32_t idx = ~(uint32_t)best;
    float2 g = ((const float2*)grid_flat)[idx];
    ((float2*)out)[b] = g;
}

// ===========================================================================
// Fallback path (round-1, proven correct, needs only 2.36 MB ws)
// ===========================================================================
#define MTILES  128
#define MTILE   (M / MTILES)
#define BTILE   256

__global__ __launch_bounds__(BTILE, 8)
void som_score_kernel(const float* __restrict__ x,
                      const float* __restrict__ w,
                      const float* __restrict__ wnorm,
                      float* __restrict__ pscore,
                      int*   __restrict__ pidx) {
    const int bt = blockIdx.x;
    const int mt = blockIdx.y;
    const int b  = bt * BTILE + threadIdx.x;

    float xr[D];
    const float4* xp = (const float4*)(x + (size_t)b * D);
#pragma unroll
    for (int i = 0; i < D / 4; i++) {
        float4 v = xp[i];
        xr[4 * i + 0] = v.x; xr[4 * i + 1] = v.y;
        xr[4 * i + 2] = v.z; xr[4 * i + 3] = v.w;
    }

    const int m0 = mt * MTILE;
    float best = -3.0e38f;
    int   bidx = m0;
#pragma unroll 2
    for (int mm = 0; mm < MTILE; mm++) {
        const int m = m0 + mm;
        const float* __restrict__ wr = w + (size_t)m * D;
        float acc = 0.0f;
#pragma unroll
        for (int i = 0; i < D; i++) acc = fmaf(xr[i], wr[i], acc);
        const float score = acc - wnorm[m];
        if (score > best) { best = score; bidx = m; }
    }
    pscore[(size_t)b * MTILES + mt] = best;
    pidx  [(size_t)b * MTILES + mt] = bidx;
}

__global__ void som_reduce_kernel(const float* __restrict__ pscore,
                                  const int*   __restrict__ pidx,
                                  const float* __restrict__ grid_flat,
                                  float* __restrict__ out) {
    const int b = blockIdx.x * blockDim.x + threadIdx.x;
    const float* ps = pscore + (size_t)b * MTILES;
    const int*   pi = pidx   + (size_t)b * MTILES;
    float best = -3.0e38f;
    int   bidx = 0x7fffffff;
#pragma unroll 4
    for (int t = 0; t < MTILES; t++) {
        const float s  = ps[t];
        const int   id = pi[t];
        if (s > best || (s == best && id < bidx)) { best = s; bidx = id; }
    }
    const float2 g = ((const float2*)grid_flat)[bidx];
    ((float2*)out)[b] = g;
}

// ===========================================================================
extern "C" void kernel_launch(void* const* d_in, const int* in_sizes, int n_in,
                              void* d_out, int out_size, void* d_ws, size_t ws_size,
                              hipStream_t stream) {
    const float* x         = (const float*)d_in[0];   // [B, D]
    const float* grid_flat = (const float*)d_in[1];   // [1, M, 2]
    const float* w         = (const float*)d_in[2];   // [1, M, D]
    float* out = (float*)d_out;                       // [B, 2]

    char* ws = (char*)d_ws;
    const size_t XH_OFF   = 0;
    const size_t XL_OFF   = XH_OFF + (size_t)B * D * sizeof(_Float16);     // 128K
    const size_t WN_OFF   = XL_OFF + (size_t)B * D * sizeof(_Float16);     // 256K
    const size_t PK_OFF   = WN_OFF + (size_t)M * sizeof(float);            // 512K
    const size_t S2_OFF   = PK_OFF + (size_t)STRIPS * B * sizeof(uint64_t);
    const size_t NEED     = S2_OFF + (size_t)SGROUPS * B * sizeof(uint64_t);

    if (ws_size >= NEED) {
        _Float16* x_hi  = (_Float16*)(ws + XH_OFF);
        _Float16* x_lo  = (_Float16*)(ws + XL_OFF);
        float*    wnorm = (float*)(ws + WN_OFF);
        uint64_t* pkeys = (uint64_t*)(ws + PK_OFF);
        uint64_t* s2    = (uint64_t*)(ws + S2_OFF);

        som_wnorm_kernel<<<(M * 4) / 256, 256, 0, stream>>>(w, wnorm);
        split_x_kernel<<<(B * D) / 256, 256, 0, stream>>>(x, x_hi, x_lo);
        som_mfma_kernel<<<STRIPS, 256, 0, stream>>>(w, wnorm, x_hi, x_lo, pkeys);
        som_reduce1_kernel<<<dim3(B / 256, SGROUPS), 256, 0, stream>>>(pkeys, s2);
        som_reduce2_kernel<<<B / 256, 256, 0, stream>>>(s2, grid_flat, out);
    } else {
        // fallback: round-1 fp32 VALU path (2.36 MB ws)
        float* wnorm  = (float*)d_ws;
        float* pscore = wnorm + M;
        int*   pidx   = (int*)(pscore + (size_t)B * MTILES);

        som_wnorm_kernel<<<(M * 4) / 256, 256, 0, stream>>>(w, wnorm);
        dim3 grid1(B / BTILE, MTILES);
        som_score_kernel<<<grid1, BTILE, 0, stream>>>(x, w, wnorm, pscore, pidx);
        som_reduce_kernel<<<B / 256, 256, 0, stream>>>(pscore, pidx, grid_flat, out);
    }
}

// Round 3
// 101.841 us; speedup vs baseline: 3.0917x; 1.0944x over previous
//
#include <hip/hip_runtime.h>
#include <stdint.h>

// Problem constants
#define D       32
#define B       2048
#define M       65536
#define STRIPS  1024          // M / 64 rows per strip
#define CHUNKS  4             // batch chunks (one per wave in a main block)
#define CHCOLS  (B / CHUNKS)  // 512 cols per chunk
#define NTILES  (CHCOLS / 16) // 32 16-col tiles per wave-job
#define SGROUPS 32            // strip groups in reduce1
#define SPERG   (STRIPS / SGROUPS)  // 32 strips per group

typedef _Float16 half8 __attribute__((ext_vector_type(8)));
typedef float    floatx4 __attribute__((ext_vector_type(4)));

// ---------------------------------------------------------------------------
// fast-path ws layout (16B aligned):
//   [0,       128K)     x_hi  _Float16[B*D]
//   [128K,    256K)     x_lo  _Float16[B*D]
//   [256K,    512K)     wnorm float[M]        (0.5*||w||^2, positive)
//   [512K,    512K+8M)  pmax  uint32[STRIPS*B] (sortable max score per strip,col)
//   [+8M,     +512K)    s2    uint64[SGROUPS*B] ((max<<32)|~strip per group,col)
// ---------------------------------------------------------------------------

__device__ __forceinline__ uint32_t f32_sortable(float f) {
    uint32_t u = __float_as_uint(f);
    u ^= (uint32_t)((int32_t)u >> 31) | 0x80000000u;
    return u;
}

// ============ prep (fused): 0.5*||w||^2 and x -> fp16 hi/lo ================
__global__ void som_prep_kernel(const float* __restrict__ w,
                                const float* __restrict__ x,
                                float* __restrict__ wnorm,
                                _Float16* __restrict__ xh,
                                _Float16* __restrict__ xl) {
    if (blockIdx.x < (M * 4) / 256) {
        // wnorm: 4 threads per row, float4 loads, shuffle-reduce
        int t   = blockIdx.x * 256 + threadIdx.x;
        int row = t >> 2;
        int j   = t & 3;
        const float4* p = (const float4*)(w + (size_t)row * D) + j * 2;
        float4 a = p[0];
        float4 b4 = p[1];
        float s = a.x * a.x + a.y * a.y + a.z * a.z + a.w * a.w
                + b4.x * b4.x + b4.y * b4.y + b4.z * b4.z + b4.w * b4.w;
        s += __shfl_xor(s, 1);
        s += __shfl_xor(s, 2);
        if (j == 0) wnorm[row] = 0.5f * s;
    } else {
        int i = (blockIdx.x - (M * 4) / 256) * 256 + threadIdx.x;  // B*D
        float v = x[i];
        _Float16 h = (_Float16)v;
        xh[i] = h;
        xl[i] = (_Float16)(v - (float)h);
    }
}

// ============ phase 1: MFMA, per-(strip,col) MAX only ======================
// Wave owns a 64-row w strip (A-frags, fp32->f16 hi/lo split in regs, amortized
// over 32 col-tiles). -0.5||w||^2 rides in the accumulator init. Epilogue per
// tile: fmax tree over 16 C regs + quad butterfly + sortable-u32 store.
__global__ __launch_bounds__(256, 4)
void som_mfma_kernel(const float* __restrict__ w,
                     const float* __restrict__ wnorm,
                     const _Float16* __restrict__ x_hi,
                     const _Float16* __restrict__ x_lo,
                     uint32_t* __restrict__ pmax) {
    const int s    = blockIdx.x;            // strip 0..1023
    const int wv   = threadIdx.x >> 6;      // chunk 0..3
    const int lane = threadIdx.x & 63;
    const int q    = lane >> 4;             // quad 0..3
    const int j    = lane & 15;

    // A-frags: A[m=lane&15][k=q*8+kk]; 4 row-tiles cover 64 rows.
    half8 a_hi[4], a_lo[4];
#pragma unroll
    for (int t = 0; t < 4; t++) {
        const float* wp = w + (size_t)(s * 64 + t * 16 + j) * D + q * 8;
        float4 f0 = ((const float4*)wp)[0];
        float4 f1 = ((const float4*)wp)[1];
        float f[8] = {f0.x, f0.y, f0.z, f0.w, f1.x, f1.y, f1.z, f1.w};
#pragma unroll
        for (int k = 0; k < 8; k++) {
            _Float16 h = (_Float16)f[k];
            a_hi[t][k] = h;
            a_lo[t][k] = (_Float16)(f[k] - (float)h);
        }
    }

    // accumulator init = -wnorm for this lane's C rows (row = t*16 + q*4 + r)
    floatx4 init[4];
#pragma unroll
    for (int t = 0; t < 4; t++)
#pragma unroll
        for (int r = 0; r < 4; r++)
            init[t][r] = -wnorm[s * 64 + t * 16 + q * 4 + r];

    uint32_t* pm = pmax + (size_t)s * B;

#pragma unroll 2
    for (int it = 0; it < NTILES; it++) {
        const int col = wv * CHCOLS + it * 16 + j;
        const half8 bh = *(const half8*)(x_hi + (size_t)col * D + q * 8);
        const half8 bl = *(const half8*)(x_lo + (size_t)col * D + q * 8);

        floatx4 acc[4];
#pragma unroll
        for (int t = 0; t < 4; t++)
            acc[t] = __builtin_amdgcn_mfma_f32_16x16x32_f16(a_lo[t], bh, init[t], 0, 0, 0);
#pragma unroll
        for (int t = 0; t < 4; t++)
            acc[t] = __builtin_amdgcn_mfma_f32_16x16x32_f16(a_hi[t], bl, acc[t], 0, 0, 0);
#pragma unroll
        for (int t = 0; t < 4; t++)
            acc[t] = __builtin_amdgcn_mfma_f32_16x16x32_f16(a_hi[t], bh, acc[t], 0, 0, 0);

        // max over 16 C values (no index tracking)
        float b0 = fmaxf(fmaxf(acc[0][0], acc[0][1]), fmaxf(acc[0][2], acc[0][3]));
        float b1 = fmaxf(fmaxf(acc[1][0], acc[1][1]), fmaxf(acc[1][2], acc[1][3]));
        float b2 = fmaxf(fmaxf(acc[2][0], acc[2][1]), fmaxf(acc[2][2], acc[2][3]));
        float b3 = fmaxf(fmaxf(acc[3][0], acc[3][1]), fmaxf(acc[3][2], acc[3][3]));
        float best = fmaxf(fmaxf(b0, b1), fmaxf(b2, b3));

        // butterfly max across the 4 quads (same col j)
        best = fmaxf(best, __shfl_xor(best, 16));
        best = fmaxf(best, __shfl_xor(best, 32));

        if (lane < 16) pm[col] = f32_sortable(best);
    }
}

// ============ reduce1: max over strips within group, keep lowest strip =====
__global__ void som_reduce1_kernel(const uint32_t* __restrict__ pmax,
                                   uint64_t* __restrict__ s2) {
    const int col = blockIdx.x * 256 + threadIdx.x;  // gridDim.x = B/256
    const int sg  = blockIdx.y;                      // 0..SGROUPS-1
    uint32_t best = pmax[(size_t)(sg * SPERG) * B + col];
    int bstrip = sg * SPERG;
#pragma unroll 8
    for (int t = 1; t < SPERG; t++) {
        uint32_t u = pmax[(size_t)(sg * SPERG + t) * B + col];
        if (u > best) { best = u; bstrip = sg * SPERG + t; }  // strict > => lowest strip
    }
    s2[(size_t)sg * B + col] = ((uint64_t)best << 32) | (uint32_t)(~(uint32_t)bstrip);
}

// ============ final: pick strip, fp32 re-argmax within it, gather ==========
// One wave per col. Lanes 0..31 reduce the 32 group keys -> winning strip
// (lowest strip on tie). Then lane l computes exact fp32 score of row
// strip*64+l, wave-argmax with lowest-row tie-break, lane 0 gathers coords.
__global__ __launch_bounds__(256)
void som_final_kernel(const uint64_t* __restrict__ s2,
                      const float* __restrict__ x,
                      const float* __restrict__ w,
                      const float* __restrict__ wnorm,
                      const float* __restrict__ grid_flat,
                      float* __restrict__ out) {
    const int wv   = threadIdx.x >> 6;
    const int lane = threadIdx.x & 63;
    const int col  = blockIdx.x * 4 + wv;            // gridDim.x = B/4

    // winner strip: max over 32 group keys (lanes >=32 contribute 0 = -inf)
    uint64_t k = (lane < SGROUPS) ? s2[(size_t)lane * B + col] : 0ull;
    {
        uint64_t o;
        o = (uint64_t)__shfl_xor((long long)k,  1); if (o > k) k = o;
        o = (uint64_t)__shfl_xor((long long)k,  2); if (o > k) k = o;
        o = (uint64_t)__shfl_xor((long long)k,  4); if (o > k) k = o;
        o = (uint64_t)__shfl_xor((long long)k,  8); if (o > k) k = o;
        o = (uint64_t)__shfl_xor((long long)k, 16); if (o > k) k = o;
        o = (uint64_t)__shfl_xor((long long)k, 32); if (o > k) k = o;
    }
    const int strip = (int)(~(uint32_t)k);
    const int row   = strip * 64 + lane;

    // exact fp32 score for this lane's row
    const float* xc = x + (size_t)col * D;           // wave-uniform
    const float* wr = w + (size_t)row * D;
    float acc = 0.0f;
#pragma unroll
    for (int i = 0; i < D; i++) acc = fmaf(xc[i], wr[i], acc);
    const float score = acc - wnorm[row];

    // wave argmax, lowest row on tie
    uint64_t key = ((uint64_t)f32_sortable(score) << 32) | (uint32_t)(~(uint32_t)row);
    {
        uint64_t o;
        o = (uint64_t)__shfl_xor((long long)key,  1); if (o > key) key = o;
        o = (uint64_t)__shfl_xor((long long)key,  2); if (o > key) key = o;
        o = (uint64_t)__shfl_xor((long long)key,  4); if (o > key) key = o;
        o = (uint64_t)__shfl_xor((long long)key,  8); if (o > key) key = o;
        o = (uint64_t)__shfl_xor((long long)key, 16); if (o > key) key = o;
        o = (uint64_t)__shfl_xor((long long)key, 32); if (o > key) key = o;
    }
    if (lane == 0) {
        const uint32_t idx = ~(uint32_t)key;
        ((float2*)out)[col] = ((const float2*)grid_flat)[idx];
    }
}

// ===========================================================================
// Fallback path (round-1, proven correct, needs only 2.36 MB ws)
// ===========================================================================
#define MTILES  128
#define MTILE   (M / MTILES)
#define BTILE   256

__global__ void som_wnorm_kernel(const float* __restrict__ w,
                                 float* __restrict__ wnorm) {
    int t   = blockIdx.x * blockDim.x + threadIdx.x;
    int row = t >> 2;
    int j   = t & 3;
    const float4* p = (const float4*)(w + (size_t)row * D) + j * 2;
    float4 a = p[0];
    float4 b4 = p[1];
    float s = a.x * a.x + a.y * a.y + a.z * a.z + a.w * a.w
            + b4.x * b4.x + b4.y * b4.y + b4.z * b4.z + b4.w * b4.w;
    s += __shfl_xor(s, 1);
    s += __shfl_xor(s, 2);
    if (j == 0) wnorm[row] = 0.5f * s;
}

__global__ __launch_bounds__(BTILE, 8)
void som_score_kernel(const float* __restrict__ x,
                      const float* __restrict__ w,
                      const float* __restrict__ wnorm,
                      float* __restrict__ pscore,
                      int*   __restrict__ pidx) {
    const int bt = blockIdx.x;
    const int mt = blockIdx.y;
    const int b  = bt * BTILE + threadIdx.x;

    float xr[D];
    const float4* xp = (const float4*)(x + (size_t)b * D);
#pragma unroll
    for (int i = 0; i < D / 4; i++) {
        float4 v = xp[i];
        xr[4 * i + 0] = v.x; xr[4 * i + 1] = v.y;
        xr[4 * i + 2] = v.z; xr[4 * i + 3] = v.w;
    }

    const int m0 = mt * MTILE;
    float best = -3.0e38f;
    int   bidx = m0;
#pragma unroll 2
    for (int mm = 0; mm < MTILE; mm++) {
        const int m = m0 + mm;
        const float* __restrict__ wr = w + (size_t)m * D;
        float acc = 0.0f;
#pragma unroll
        for (int i = 0; i < D; i++) acc = fmaf(xr[i], wr[i], acc);
        const float score = acc - wnorm[m];
        if (score > best) { best = score; bidx = m; }
    }
    pscore[(size_t)b * MTILES + mt] = best;
    pidx  [(size_t)b * MTILES + mt] = bidx;
}

__global__ void som_reduce_kernel(const float* __restrict__ pscore,
                                  const int*   __restrict__ pidx,
                                  const float* __restrict__ grid_flat,
                                  float* __restrict__ out) {
    const int b = blockIdx.x * blockDim.x + threadIdx.x;
    const float* ps = pscore + (size_t)b * MTILES;
    const int*   pi = pidx   + (size_t)b * MTILES;
    float best = -3.0e38f;
    int   bidx = 0x7fffffff;
#pragma unroll 4
    for (int t = 0; t < MTILES; t++) {
        const float s  = ps[t];
        const int   id = pi[t];
        if (s > best || (s == best && id < bidx)) { best = s; bidx = id; }
    }
    ((float2*)out)[b] = ((const float2*)grid_flat)[bidx];
}

// ===========================================================================
extern "C" void kernel_launch(void* const* d_in, const int* in_sizes, int n_in,
                              void* d_out, int out_size, void* d_ws, size_t ws_size,
                              hipStream_t stream) {
    const float* x         = (const float*)d_in[0];   // [B, D]
    const float* grid_flat = (const float*)d_in[1];   // [1, M, 2]
    const float* w         = (const float*)d_in[2];   // [1, M, D]
    float* out = (float*)d_out;                       // [B, 2]

    char* ws = (char*)d_ws;
    const size_t XH_OFF = 0;
    const size_t XL_OFF = XH_OFF + (size_t)B * D * sizeof(_Float16);
    const size_t WN_OFF = XL_OFF + (size_t)B * D * sizeof(_Float16);
    const size_t PM_OFF = WN_OFF + (size_t)M * sizeof(float);
    const size_t S2_OFF = PM_OFF + (size_t)STRIPS * B * sizeof(uint32_t);
    const size_t NEED   = S2_OFF + (size_t)SGROUPS * B * sizeof(uint64_t);

    if (ws_size >= NEED) {
        _Float16* x_hi  = (_Float16*)(ws + XH_OFF);
        _Float16* x_lo  = (_Float16*)(ws + XL_OFF);
        float*    wnorm = (float*)(ws + WN_OFF);
        uint32_t* pmax  = (uint32_t*)(ws + PM_OFF);
        uint64_t* s2    = (uint64_t*)(ws + S2_OFF);

        som_prep_kernel<<<(M * 4) / 256 + (B * D) / 256, 256, 0, stream>>>(
            w, x, wnorm, x_hi, x_lo);
        som_mfma_kernel<<<STRIPS, 256, 0, stream>>>(w, wnorm, x_hi, x_lo, pmax);
        som_reduce1_kernel<<<dim3(B / 256, SGROUPS), 256, 0, stream>>>(pmax, s2);
        som_final_kernel<<<B / 4, 256, 0, stream>>>(s2, x, w, wnorm, grid_flat, out);
    } else {
        float* wnorm  = (float*)d_ws;
        float* pscore = wnorm + M;
        int*   pidx   = (int*)(pscore + (size_t)B * MTILES);

        som_wnorm_kernel<<<(M * 4) / 256, 256, 0, stream>>>(w, wnorm);
        dim3 grid1(B / BTILE, MTILES);
        som_score_kernel<<<grid1, BTILE, 0, stream>>>(x, w, wnorm, pscore, pidx);
        som_reduce_kernel<<<B / 256, 256, 0, stream>>>(pscore, pidx, grid_flat, out);
    }
}

// Round 4
// 99.945 us; speedup vs baseline: 3.1504x; 1.0190x over previous
//
#include <hip/hip_runtime.h>
#include <stdint.h>

// Problem constants
#define D       32
#define B       2048
#define M       65536
#define STRIPS  1024          // M / 64 rows per strip
#define CHUNKS  4             // batch chunks (one per wave in a main block)
#define CHCOLS  (B / CHUNKS)  // 512 cols per chunk
#define NTILES  (CHCOLS / 16) // 32 16-col tiles per wave-job
#define SGROUPS 32            // strip groups in reduce1
#define SPERG   (STRIPS / SGROUPS)  // 32 strips per group

typedef _Float16 half8  __attribute__((ext_vector_type(8)));
typedef _Float16 half4v __attribute__((ext_vector_type(4)));
typedef float    floatx4 __attribute__((ext_vector_type(4)));

// ---------------------------------------------------------------------------
// fast-path ws layout (16B aligned):
//   [0,     128K)     x_hi  _Float16[B*D]
//   [128K,  256K)     x_lo  _Float16[B*D]
//   [256K,  256K+8M)  pmax  uint32[STRIPS*B]  (sortable max score per strip,col)
//   [+8M,   +512K)    s2    uint64[SGROUPS*B] ((max<<32)|~strip per group,col)
// ---------------------------------------------------------------------------

__device__ __forceinline__ uint32_t f32_sortable(float f) {
    uint32_t u = __float_as_uint(f);
    u ^= (uint32_t)((int32_t)u >> 31) | 0x80000000u;
    return u;
}

// ============ prep: x -> fp16 hi/lo (float4 in, half4 out) =================
__global__ void som_prep_kernel(const float* __restrict__ x,
                                _Float16* __restrict__ xh,
                                _Float16* __restrict__ xl) {
    int i = (blockIdx.x * 256 + threadIdx.x) * 4;   // B*D/4 threads = 64 blocks
    float4 v = *(const float4*)(x + i);
    half4v h, l;
    h[0] = (_Float16)v.x; l[0] = (_Float16)(v.x - (float)h[0]);
    h[1] = (_Float16)v.y; l[1] = (_Float16)(v.y - (float)h[1]);
    h[2] = (_Float16)v.z; l[2] = (_Float16)(v.z - (float)h[2]);
    h[3] = (_Float16)v.w; l[3] = (_Float16)(v.w - (float)h[3]);
    *(half4v*)(xh + i) = h;
    *(half4v*)(xl + i) = l;
}

// ============ phase 1: MFMA, per-(strip,col) MAX only ======================
// Wave owns a 64-row w strip. A-frags fp32->f16 hi/lo split in regs; strip
// norms computed in-register from the same loads (shfl butterflies) and folded
// into the accumulator init. Epilogue per tile: fmax tree + quad butterfly +
// sortable-u32 store.
__global__ __launch_bounds__(256, 4)
void som_mfma_kernel(const float* __restrict__ w,
                     const _Float16* __restrict__ x_hi,
                     const _Float16* __restrict__ x_lo,
                     uint32_t* __restrict__ pmax) {
    const int s    = blockIdx.x;            // strip 0..1023
    const int wv   = threadIdx.x >> 6;      // chunk 0..3
    const int lane = threadIdx.x & 63;
    const int q    = lane >> 4;             // quad 0..3
    const int j    = lane & 15;

    // A-frags: A[m=lane&15][k=q*8+kk]; 4 row-tiles cover 64 rows.
    // nrm[t] = full ||w_{t*16+j}||^2 after cross-quad butterfly.
    half8 a_hi[4], a_lo[4];
    float nrm[4];
#pragma unroll
    for (int t = 0; t < 4; t++) {
        const float* wp = w + (size_t)(s * 64 + t * 16 + j) * D + q * 8;
        float4 f0 = ((const float4*)wp)[0];
        float4 f1 = ((const float4*)wp)[1];
        float f[8] = {f0.x, f0.y, f0.z, f0.w, f1.x, f1.y, f1.z, f1.w};
        float sq = 0.0f;
#pragma unroll
        for (int k = 0; k < 8; k++) {
            _Float16 h = (_Float16)f[k];
            a_hi[t][k] = h;
            a_lo[t][k] = (_Float16)(f[k] - (float)h);
            sq = fmaf(f[k], f[k], sq);
        }
        sq += __shfl_xor(sq, 16);
        sq += __shfl_xor(sq, 32);
        nrm[t] = sq;
    }

    // accumulator init = -0.5*||w_row||^2 for this lane's C rows
    // (row = t*16 + q*4 + r; lane q*4+r holds nrm for that row)
    floatx4 init[4];
#pragma unroll
    for (int t = 0; t < 4; t++)
#pragma unroll
        for (int r = 0; r < 4; r++)
            init[t][r] = -0.5f * __shfl(nrm[t], q * 4 + r);

    uint32_t* pm = pmax + (size_t)s * B;

#pragma unroll 2
    for (int it = 0; it < NTILES; it++) {
        const int col = wv * CHCOLS + it * 16 + j;
        const half8 bh = *(const half8*)(x_hi + (size_t)col * D + q * 8);
        const half8 bl = *(const half8*)(x_lo + (size_t)col * D + q * 8);

        floatx4 acc[4];
#pragma unroll
        for (int t = 0; t < 4; t++)
            acc[t] = __builtin_amdgcn_mfma_f32_16x16x32_f16(a_lo[t], bh, init[t], 0, 0, 0);
#pragma unroll
        for (int t = 0; t < 4; t++)
            acc[t] = __builtin_amdgcn_mfma_f32_16x16x32_f16(a_hi[t], bl, acc[t], 0, 0, 0);
#pragma unroll
        for (int t = 0; t < 4; t++)
            acc[t] = __builtin_amdgcn_mfma_f32_16x16x32_f16(a_hi[t], bh, acc[t], 0, 0, 0);

        // max over 16 C values (no index tracking)
        float b0 = fmaxf(fmaxf(acc[0][0], acc[0][1]), fmaxf(acc[0][2], acc[0][3]));
        float b1 = fmaxf(fmaxf(acc[1][0], acc[1][1]), fmaxf(acc[1][2], acc[1][3]));
        float b2 = fmaxf(fmaxf(acc[2][0], acc[2][1]), fmaxf(acc[2][2], acc[2][3]));
        float b3 = fmaxf(fmaxf(acc[3][0], acc[3][1]), fmaxf(acc[3][2], acc[3][3]));
        float best = fmaxf(fmaxf(b0, b1), fmaxf(b2, b3));

        // butterfly max across the 4 quads (same col j)
        best = fmaxf(best, __shfl_xor(best, 16));
        best = fmaxf(best, __shfl_xor(best, 32));

        if (lane < 16) pm[col] = f32_sortable(best);
    }
}

// ============ reduce1: max over strips within group, keep lowest strip =====
__global__ void som_reduce1_kernel(const uint32_t* __restrict__ pmax,
                                   uint64_t* __restrict__ s2) {
    const int col = blockIdx.x * 256 + threadIdx.x;  // gridDim.x = B/256
    const int sg  = blockIdx.y;                      // 0..SGROUPS-1
    uint32_t best = pmax[(size_t)(sg * SPERG) * B + col];
    int bstrip = sg * SPERG;
#pragma unroll 8
    for (int t = 1; t < SPERG; t++) {
        uint32_t u = pmax[(size_t)(sg * SPERG + t) * B + col];
        if (u > best) { best = u; bstrip = sg * SPERG + t; }  // strict > => lowest strip
    }
    s2[(size_t)sg * B + col] = ((uint64_t)best << 32) | (uint32_t)(~(uint32_t)bstrip);
}

// ============ final: pick strip, fp32 re-argmax within it, gather ==========
// One wave per col. Lanes 0..31 reduce the 32 group keys -> winning strip
// (lowest strip on tie). Lane l computes exact fp32 score of row strip*64+l
// (norm inline), wave-argmax with lowest-row tie-break, lane 0 gathers coords.
__global__ __launch_bounds__(256)
void som_final_kernel(const uint64_t* __restrict__ s2,
                      const float* __restrict__ x,
                      const float* __restrict__ w,
                      const float* __restrict__ grid_flat,
                      float* __restrict__ out) {
    const int wv   = threadIdx.x >> 6;
    const int lane = threadIdx.x & 63;
    const int col  = blockIdx.x * 4 + wv;            // gridDim.x = B/4

    // winner strip: max over 32 group keys (lanes >=32 contribute 0)
    uint64_t k = (lane < SGROUPS) ? s2[(size_t)lane * B + col] : 0ull;
    {
        uint64_t o;
        o = (uint64_t)__shfl_xor((long long)k,  1); if (o > k) k = o;
        o = (uint64_t)__shfl_xor((long long)k,  2); if (o > k) k = o;
        o = (uint64_t)__shfl_xor((long long)k,  4); if (o > k) k = o;
        o = (uint64_t)__shfl_xor((long long)k,  8); if (o > k) k = o;
        o = (uint64_t)__shfl_xor((long long)k, 16); if (o > k) k = o;
        o = (uint64_t)__shfl_xor((long long)k, 32); if (o > k) k = o;
    }
    const int strip = (int)(~(uint32_t)k);
    const int row   = strip * 64 + lane;

    // exact fp32 score for this lane's row (norm computed inline)
    const float* xc = x + (size_t)col * D;           // wave-uniform
    const float* wr = w + (size_t)row * D;
    float acc = 0.0f, nn = 0.0f;
#pragma unroll
    for (int i = 0; i < D; i++) {
        const float wv_ = wr[i];
        acc = fmaf(xc[i], wv_, acc);
        nn  = fmaf(wv_, wv_, nn);
    }
    const float score = acc - 0.5f * nn;

    // wave argmax, lowest row on tie
    uint64_t key = ((uint64_t)f32_sortable(score) << 32) | (uint32_t)(~(uint32_t)row);
    {
        uint64_t o;
        o = (uint64_t)__shfl_xor((long long)key,  1); if (o > key) key = o;
        o = (uint64_t)__shfl_xor((long long)key,  2); if (o > key) key = o;
        o = (uint64_t)__shfl_xor((long long)key,  4); if (o > key) key = o;
        o = (uint64_t)__shfl_xor((long long)key,  8); if (o > key) key = o;
        o = (uint64_t)__shfl_xor((long long)key, 16); if (o > key) key = o;
        o = (uint64_t)__shfl_xor((long long)key, 32); if (o > key) key = o;
    }
    if (lane == 0) {
        const uint32_t idx = ~(uint32_t)key;
        ((float2*)out)[col] = ((const float2*)grid_flat)[idx];
    }
}

// ===========================================================================
// Fallback path (round-1, proven correct, needs only 2.36 MB ws)
// ===========================================================================
#define MTILES  128
#define MTILE   (M / MTILES)
#define BTILE   256

__global__ void som_wnorm_kernel(const float* __restrict__ w,
                                 float* __restrict__ wnorm) {
    int t   = blockIdx.x * blockDim.x + threadIdx.x;
    int row = t >> 2;
    int j   = t & 3;
    const float4* p = (const float4*)(w + (size_t)row * D) + j * 2;
    float4 a = p[0];
    float4 b4 = p[1];
    float s = a.x * a.x + a.y * a.y + a.z * a.z + a.w * a.w
            + b4.x * b4.x + b4.y * b4.y + b4.z * b4.z + b4.w * b4.w;
    s += __shfl_xor(s, 1);
    s += __shfl_xor(s, 2);
    if (j == 0) wnorm[row] = 0.5f * s;
}

__global__ __launch_bounds__(BTILE, 8)
void som_score_kernel(const float* __restrict__ x,
                      const float* __restrict__ w,
                      const float* __restrict__ wnorm,
                      float* __restrict__ pscore,
                      int*   __restrict__ pidx) {
    const int bt = blockIdx.x;
    const int mt = blockIdx.y;
    const int b  = bt * BTILE + threadIdx.x;

    float xr[D];
    const float4* xp = (const float4*)(x + (size_t)b * D);
#pragma unroll
    for (int i = 0; i < D / 4; i++) {
        float4 v = xp[i];
        xr[4 * i + 0] = v.x; xr[4 * i + 1] = v.y;
        xr[4 * i + 2] = v.z; xr[4 * i + 3] = v.w;
    }

    const int m0 = mt * MTILE;
    float best = -3.0e38f;
    int   bidx = m0;
#pragma unroll 2
    for (int mm = 0; mm < MTILE; mm++) {
        const int m = m0 + mm;
        const float* __restrict__ wr = w + (size_t)m * D;
        float acc = 0.0f;
#pragma unroll
        for (int i = 0; i < D; i++) acc = fmaf(xr[i], wr[i], acc);
        const float score = acc - wnorm[m];
        if (score > best) { best = score; bidx = m; }
    }
    pscore[(size_t)b * MTILES + mt] = best;
    pidx  [(size_t)b * MTILES + mt] = bidx;
}

__global__ void som_reduce_kernel(const float* __restrict__ pscore,
                                  const int*   __restrict__ pidx,
                                  const float* __restrict__ grid_flat,
                                  float* __restrict__ out) {
    const int b = blockIdx.x * blockDim.x + threadIdx.x;
    const float* ps = pscore + (size_t)b * MTILES;
    const int*   pi = pidx   + (size_t)b * MTILES;
    float best = -3.0e38f;
    int   bidx = 0x7fffffff;
#pragma unroll 4
    for (int t = 0; t < MTILES; t++) {
        const float s  = ps[t];
        const int   id = pi[t];
        if (s > best || (s == best && id < bidx)) { best = s; bidx = id; }
    }
    ((float2*)out)[b] = ((const float2*)grid_flat)[bidx];
}

// ===========================================================================
extern "C" void kernel_launch(void* const* d_in, const int* in_sizes, int n_in,
                              void* d_out, int out_size, void* d_ws, size_t ws_size,
                              hipStream_t stream) {
    const float* x         = (const float*)d_in[0];   // [B, D]
    const float* grid_flat = (const float*)d_in[1];   // [1, M, 2]
    const float* w         = (const float*)d_in[2];   // [1, M, D]
    float* out = (float*)d_out;                       // [B, 2]

    char* ws = (char*)d_ws;
    const size_t XH_OFF = 0;
    const size_t XL_OFF = XH_OFF + (size_t)B * D * sizeof(_Float16);
    const size_t PM_OFF = XL_OFF + (size_t)B * D * sizeof(_Float16);
    const size_t S2_OFF = PM_OFF + (size_t)STRIPS * B * sizeof(uint32_t);
    const size_t NEED   = S2_OFF + (size_t)SGROUPS * B * sizeof(uint64_t);

    if (ws_size >= NEED) {
        _Float16* x_hi = (_Float16*)(ws + XH_OFF);
        _Float16* x_lo = (_Float16*)(ws + XL_OFF);
        uint32_t* pmax = (uint32_t*)(ws + PM_OFF);
        uint64_t* s2   = (uint64_t*)(ws + S2_OFF);

        som_prep_kernel<<<(B * D / 4) / 256, 256, 0, stream>>>(x, x_hi, x_lo);
        som_mfma_kernel<<<STRIPS, 256, 0, stream>>>(w, x_hi, x_lo, pmax);
        som_reduce1_kernel<<<dim3(B / 256, SGROUPS), 256, 0, stream>>>(pmax, s2);
        som_final_kernel<<<B / 4, 256, 0, stream>>>(s2, x, w, grid_flat, out);
    } else {
        float* wnorm  = (float*)d_ws;
        float* pscore = wnorm + M;
        int*   pidx   = (int*)(pscore + (size_t)B * MTILES);

        som_wnorm_kernel<<<(M * 4) / 256, 256, 0, stream>>>(w, wnorm);
        dim3 grid1(B / BTILE, MTILES);
        som_score_kernel<<<grid1, BTILE, 0, stream>>>(x, w, wnorm, pscore, pidx);
        som_reduce_kernel<<<B / 256, 256, 0, stream>>>(pscore, pidx, grid_flat, out);
    }
}